// Round 3
// baseline (243.790 us; speedup 1.0000x reference)
//
#include <hip/hip_runtime.h>

typedef __attribute__((ext_vector_type(8))) short bf16x8;
typedef __attribute__((ext_vector_type(4))) float f32x4;

#define NTOT 16384
#define MCODES 2048
#define DDIM 256

__device__ __forceinline__ unsigned short f2bf(float f) {
  union { float f; unsigned u; } v; v.f = f;
  unsigned r = v.u + 0x7FFFu + ((v.u >> 16) & 1u);   // RNE
  return (unsigned short)(r >> 16);
}

// ---------------- prep e: bf16 convert + ||e||^2 + colmin init ----------------
__global__ void prep_e_k(const float* __restrict__ e, unsigned short* __restrict__ ebf,
                         float* __restrict__ esq, unsigned* __restrict__ colmin) {
  int row = blockIdx.x * 4 + (threadIdx.x >> 6);
  int lane = threadIdx.x & 63;
  const float4 v = *(const float4*)(e + (size_t)row * DDIM + lane * 4);
  ushort4 o;
  o.x = f2bf(v.x); o.y = f2bf(v.y); o.z = f2bf(v.z); o.w = f2bf(v.w);
  *(ushort4*)(ebf + (size_t)row * DDIM + lane * 4) = o;
  float s = v.x * v.x + v.y * v.y + v.z * v.z + v.w * v.w;
  #pragma unroll
  for (int off = 32; off; off >>= 1) s += __shfl_xor(s, off, 64);
  if (lane == 0) {
    esq[row] = s;
    colmin[row] = 0x7F800000u;  // +inf
  }
}

// ---------------- fused transpose+GEMM 128x128, BK=64, A reg-staged from z ----------------
// A-tile = z[b][k0:k0+64][hw0:hw0+128] (fp32, direct), cvt->bf16 -> swizzled As.
// B-fragments read directly from L2-resident ebf (1 MB). zsq computed in-block.
__global__ __launch_bounds__(256) void gemm_k(
    const float* __restrict__ z,            // (16,256,32,32) fp32
    const unsigned short* __restrict__ ebf, // (2048,256) bf16
    const float* __restrict__ esq,
    unsigned* __restrict__ colmin, float* __restrict__ out) {
  __shared__ __align__(16) unsigned short As[2][128 * 64];  // 32 KB dbuf
  __shared__ __align__(16) float zsqt[2][128];

  const int tid = threadIdx.x;
  const int wave = tid >> 6, lane = tid & 63;
  const int wm = wave >> 1, wn = wave & 1;

  // T1: XCD-chunked swizzle (2048 % 8 == 0 -> bijective). XCD owns 16 full row-panels.
  const int bid = blockIdx.x;
  const int swz = (bid & 7) * 256 + (bid >> 3);
  const int col0 = (swz & 15) * 128;        // code tile
  const int row0 = (swz >> 4) * 128;        // z-row tile
  const int bb = row0 >> 10, hw0 = row0 & 1023;

  // A staging: thread owns hw = tid&127, k-halves kdb..kdb+31 of each BK=64 tile
  const int hw = tid & 127;
  const int kdb = (tid >> 7) * 32;
  const float* zsrc = z + (size_t)bb * 262144 + (size_t)kdb * 1024 + hw0 + hw;
  unsigned wb[4];
  #pragma unroll
  for (int g = 0; g < 4; ++g)
    wb[g] = hw * 128 + ((((kdb + 8 * g) * 2) ^ ((hw & 7) << 4)));

  // a-frag read addressing (XOR matches write swizzle; (rA+i*16)&7 == lane&7)
  const int rA = wm * 64 + (lane & 15);
  const int slot = (lane >> 4) * 16;
  const int aswz = (lane & 7) << 4;

  // b-frag global base: row = col0 + wn*64 + j*16 + (lane&15), k = t*64 + kk*32 + (lane>>4)*8
  const unsigned short* bp0 = ebf + (size_t)(col0 + wn * 64 + (lane & 15)) * DDIM + (lane >> 4) * 8;

  float regA[32];
  float zacc = 0.0f;
  f32x4 acc[4][4] = {};

  #define ALOAD(t)                                                          \
    {                                                                       \
      const float* p_ = zsrc + (size_t)(t) * 64 * 1024;                     \
      _Pragma("unroll")                                                     \
      for (int u = 0; u < 32; ++u) regA[u] = p_[(size_t)u * 1024];          \
    }

  #define AWRITE(buf)                                                       \
    {                                                                       \
      char* la_ = (char*)&As[buf][0];                                       \
      _Pragma("unroll")                                                     \
      for (int g = 0; g < 4; ++g) {                                         \
        bf16x8 pk_;                                                         \
        _Pragma("unroll")                                                   \
        for (int u = 0; u < 8; ++u) {                                       \
          float v_ = regA[g * 8 + u];                                       \
          zacc += v_ * v_;                                                  \
          pk_[u] = (short)f2bf(v_);                                         \
        }                                                                   \
        *(bf16x8*)(la_ + wb[g]) = pk_;                                      \
      }                                                                     \
    }

  ALOAD(0);
  AWRITE(0);
  __syncthreads();

  #pragma unroll
  for (int t = 0; t < 4; ++t) {
    const int cur = t & 1;
    if (t < 3) ALOAD(t + 1);                 // T14: issue early, hides under frags+MFMA

    bf16x8 av[2][4], bv[2][4];
    const char* pA = (const char*)&As[cur][0];
    #pragma unroll
    for (int kk = 0; kk < 2; ++kk) {
      #pragma unroll
      for (int i = 0; i < 4; ++i)
        av[kk][i] = *(const bf16x8*)(pA + (rA + i * 16) * 128 + ((kk * 64 + slot) ^ aswz));
      #pragma unroll
      for (int j = 0; j < 4; ++j)
        bv[kk][j] = *(const bf16x8*)(bp0 + (size_t)t * 64 + kk * 32 + (size_t)j * 16 * DDIM);
    }
    #pragma unroll
    for (int kk = 0; kk < 2; ++kk)
      #pragma unroll
      for (int i = 0; i < 4; ++i)
        #pragma unroll
        for (int j = 0; j < 4; ++j)
          acc[i][j] = __builtin_amdgcn_mfma_f32_16x16x32_bf16(av[kk][i], bv[kk][j], acc[i][j], 0, 0, 0);

    if (t < 3) {
      AWRITE(cur ^ 1);                       // dbuf: one barrier/iter is race-free
      __syncthreads();
    }
  }
  #undef ALOAD
  #undef AWRITE

  // block-local ||z||^2 for this row-panel
  zsqt[tid >> 7][hw] = zacc;
  __syncthreads();

  // epilogue: dist = zsq + esq - 2*cross, clamp>=0, NT store + column-min
  const int r0 = lane >> 4, c = lane & 15;
  float cmin[4] = {3.4e38f, 3.4e38f, 3.4e38f, 3.4e38f};
  #pragma unroll
  for (int j = 0; j < 4; ++j) {
    const int col = col0 + wn * 64 + j * 16 + c;
    const float es = esq[col];
    #pragma unroll
    for (int i = 0; i < 4; ++i) {
      const int lr = wm * 64 + i * 16 + r0 * 4;
      const int row = row0 + lr;
      const float4 za = *(const float4*)&zsqt[0][lr];
      const float4 zb = *(const float4*)&zsqt[1][lr];
      const float d0 = fmaxf(za.x + zb.x + es - 2.0f * acc[i][j][0], 0.0f);
      const float d1 = fmaxf(za.y + zb.y + es - 2.0f * acc[i][j][1], 0.0f);
      const float d2 = fmaxf(za.z + zb.z + es - 2.0f * acc[i][j][2], 0.0f);
      const float d3 = fmaxf(za.w + zb.w + es - 2.0f * acc[i][j][3], 0.0f);
      __builtin_nontemporal_store(d0, &out[(size_t)(row + 0) * MCODES + col]);
      __builtin_nontemporal_store(d1, &out[(size_t)(row + 1) * MCODES + col]);
      __builtin_nontemporal_store(d2, &out[(size_t)(row + 2) * MCODES + col]);
      __builtin_nontemporal_store(d3, &out[(size_t)(row + 3) * MCODES + col]);
      cmin[j] = fminf(cmin[j], fminf(fminf(d0, d1), fminf(d2, d3)));
    }
  }
  #pragma unroll
  for (int j = 0; j < 4; ++j) {
    float m = cmin[j];
    m = fminf(m, __shfl_xor(m, 16, 64));
    m = fminf(m, __shfl_xor(m, 32, 64));
    if (lane < 16) {
      const int col = col0 + wn * 64 + j * 16 + lane;
      atomicMin(colmin + col, __float_as_uint(m));   // dist>=0 -> uint order == float order
    }
  }
}

// ---------------- loss = mean(colmin) ----------------
__global__ void loss_k(const unsigned* __restrict__ colmin, float* __restrict__ loss) {
  __shared__ float sdata[4];
  int t = threadIdx.x;
  float s = 0.0f;
  for (int i = t; i < MCODES; i += 256) s += __uint_as_float(colmin[i]);
  #pragma unroll
  for (int off = 32; off; off >>= 1) s += __shfl_down(s, off, 64);
  if ((t & 63) == 0) sdata[t >> 6] = s;
  __syncthreads();
  if (t == 0) loss[0] = (sdata[0] + sdata[1] + sdata[2] + sdata[3]) * (1.0f / (float)MCODES);
}

extern "C" void kernel_launch(void* const* d_in, const int* in_sizes, int n_in,
                              void* d_out, int out_size, void* d_ws, size_t ws_size,
                              hipStream_t stream) {
  const float* z = (const float*)d_in[0];
  const float* e = (const float*)d_in[1];
  float* out = (float*)d_out;

  float* ws = (float*)d_ws;
  float* esq = ws;                                     // 2048 f
  unsigned* colmin = (unsigned*)(ws + MCODES);         // 2048 u32
  unsigned short* ebf = (unsigned short*)(ws + 2 * MCODES);  // 1 MB

  prep_e_k<<<MCODES / 4, 256, 0, stream>>>(e, ebf, esq, colmin);
  gemm_k<<<2048, 256, 0, stream>>>(z, ebf, esq, colmin, out);
  loss_k<<<1, 256, 0, stream>>>(colmin, out + (size_t)NTOT * MCODES);
}

// Round 4
// 196.458 us; speedup vs baseline: 1.2409x; 1.2409x over previous
//
#include <hip/hip_runtime.h>

typedef __attribute__((ext_vector_type(8))) short bf16x8;
typedef __attribute__((ext_vector_type(4))) float f32x4;

#define NTOT 16384
#define MCODES 2048
#define DDIM 256

__device__ __forceinline__ unsigned short f2bf(float f) {
  union { float f; unsigned u; } v; v.f = f;
  unsigned r = v.u + 0x7FFFu + ((v.u >> 16) & 1u);   // RNE
  return (unsigned short)(r >> 16);
}

#define GLOAD16(gptr, lptr) \
  __builtin_amdgcn_global_load_lds((const __attribute__((address_space(1))) void*)(gptr), \
                                   (__attribute__((address_space(3))) void*)(lptr), 16, 0, 0)

// ---------------- prep e: bf16 convert + ||e||^2 + colmin init ----------------
__global__ void prep_e_k(const float* __restrict__ e, unsigned short* __restrict__ ebf,
                         float* __restrict__ esq, unsigned* __restrict__ colmin) {
  int row = blockIdx.x * 4 + (threadIdx.x >> 6);
  int lane = threadIdx.x & 63;
  const float4 v = *(const float4*)(e + (size_t)row * DDIM + lane * 4);
  ushort4 o;
  o.x = f2bf(v.x); o.y = f2bf(v.y); o.z = f2bf(v.z); o.w = f2bf(v.w);
  *(ushort4*)(ebf + (size_t)row * DDIM + lane * 4) = o;
  float s = v.x * v.x + v.y * v.y + v.z * v.z + v.w * v.w;
  #pragma unroll
  for (int off = 32; off; off >>= 1) s += __shfl_xor(s, off, 64);
  if (lane == 0) {
    esq[row] = s;
    colmin[row] = 0x7F800000u;  // +inf
  }
}

// ---------------- fused transpose+GEMM 128x128, BK=64, 8 waves ----------------
// A-tile = z[b][k][hw] read direct (coalesced), cvt->bf16 -> swizzled As (reg-staged,
// issued 1 tile early). B staged via global_load_lds (linear dest, pre-swizzled src),
// double-buffered, issued 1 tile early -> inner loop has NO global latency.
__global__ __launch_bounds__(512) void gemm_k(
    const float* __restrict__ z,            // (16,256,32,32) fp32
    const unsigned short* __restrict__ ebf, // (2048,256) bf16
    const float* __restrict__ esq,
    unsigned* __restrict__ colmin, float* __restrict__ out) {
  __shared__ __align__(16) unsigned short As[2][128 * 64];   // 32 KB
  __shared__ __align__(16) unsigned short Bs[2][128 * 64];   // 32 KB
  __shared__ float zsqt[4][128];

  const int tid = threadIdx.x;
  const int wave = tid >> 6, lane = tid & 63;
  const int wm = wave >> 2, wn = wave & 3;      // 2 row-groups x 4 col-groups

  // T1: XCD-chunked swizzle (2048 % 8 == 0 -> bijective); row-panel's 16 col-blocks
  // share an XCD so z panel reads are L2-served.
  const int bid = blockIdx.x;
  const int swz = (bid & 7) * 256 + (bid >> 3);
  const int col0 = (swz & 15) * 128;            // code tile
  const int row0 = (swz >> 4) * 128;            // z-row tile
  const int bb = row0 >> 10, hw0 = row0 & 1023;

  // A staging: thread owns hw = tid&127 and 16 consecutive k (kg*16 ..)
  const int hw = tid & 127;
  const int kg = tid >> 7;                      // 0..3
  const float* zsrc = z + (size_t)bb * 262144 + (size_t)(kg * 16) * 1024 + hw0 + hw;
  const unsigned wb0 = hw * 128 + (((kg * 16) * 2) ^ ((hw & 7) << 4));
  const unsigned wb1 = hw * 128 + (((kg * 16 + 8) * 2) ^ ((hw & 7) << 4));

  // B staging (per chunk c: rows c*64 + wave*8 + (lane>>3), 16B per lane, linear dest)
  const int brow = wave * 8 + (lane >> 3);
  const int bsk = ((lane & 7) * 8) ^ (((lane >> 3) & 7) * 8);  // pre-swizzled k (bf16 units)

  // fragment read addressing (rA&7 == rB&7 == lane&7)
  const int rA = wm * 64 + (lane & 15);
  const int rB = wn * 32 + (lane & 15);
  const int slot = (lane >> 4) * 16;
  const int aswz = (lane & 7) << 4;

  float regA[16];
  float zacc = 0.0f;
  f32x4 acc[4][2] = {};

  #define STAGE_B(buf, t)                                                        \
    {                                                                            \
      _Pragma("unroll")                                                          \
      for (int c = 0; c < 2; ++c) {                                              \
        const unsigned short* src_ =                                             \
            ebf + (size_t)(col0 + c * 64 + brow) * DDIM + (t) * 64 + bsk;        \
        GLOAD16(src_, &Bs[buf][c * 4096 + wave * 512]);                          \
      }                                                                          \
    }

  #define ALOAD(t)                                                              \
    {                                                                            \
      const float* p_ = zsrc + (size_t)(t) * 65536;                              \
      _Pragma("unroll")                                                          \
      for (int u = 0; u < 16; ++u) regA[u] = p_[(size_t)u * 1024];               \
    }

  #define AWRITE(buf)                                                           \
    {                                                                            \
      bf16x8 pk0_, pk1_;                                                         \
      _Pragma("unroll")                                                          \
      for (int u = 0; u < 8; ++u) {                                              \
        float v0_ = regA[u], v1_ = regA[8 + u];                                  \
        zacc += v0_ * v0_ + v1_ * v1_;                                           \
        pk0_[u] = (short)f2bf(v0_);                                              \
        pk1_[u] = (short)f2bf(v1_);                                              \
      }                                                                          \
      char* la_ = (char*)&As[buf][0];                                            \
      *(bf16x8*)(la_ + wb0) = pk0_;                                              \
      *(bf16x8*)(la_ + wb1) = pk1_;                                              \
    }

  STAGE_B(0, 0);
  ALOAD(0);
  AWRITE(0);
  __syncthreads();

  #pragma unroll
  for (int t = 0; t < 4; ++t) {
    const int cur = t & 1;
    if (t < 3) {
      STAGE_B(cur ^ 1, t + 1);   // lands under this tile's compute; drained by barrier
      ALOAD(t + 1);              // T14 issue-early; consumed by AWRITE after MFMA
    }
    const char* pA = (const char*)&As[cur][0];
    const char* pB = (const char*)&Bs[cur][0];
    #pragma unroll
    for (int kk = 0; kk < 2; ++kk) {
      bf16x8 av[4], bv[2];
      #pragma unroll
      for (int i = 0; i < 4; ++i)
        av[i] = *(const bf16x8*)(pA + (rA + i * 16) * 128 + ((kk * 64 + slot) ^ aswz));
      #pragma unroll
      for (int j = 0; j < 2; ++j)
        bv[j] = *(const bf16x8*)(pB + (rB + j * 16) * 128 + ((kk * 64 + slot) ^ aswz));
      #pragma unroll
      for (int i = 0; i < 4; ++i)
        #pragma unroll
        for (int j = 0; j < 2; ++j)
          acc[i][j] = __builtin_amdgcn_mfma_f32_16x16x32_bf16(av[i], bv[j], acc[i][j], 0, 0, 0);
    }
    if (t < 3) {
      AWRITE(cur ^ 1);
      __syncthreads();
    }
  }
  #undef STAGE_B
  #undef ALOAD
  #undef AWRITE

  // block-local ||z||^2 partials (4 k-groups per row)
  zsqt[kg][hw] = zacc;
  __syncthreads();

  // epilogue: dist = zsq + esq - 2*cross, clamp>=0, NT store + column-min
  const int r0 = lane >> 4, c = lane & 15;
  float cmin[2] = {3.4e38f, 3.4e38f};
  #pragma unroll
  for (int i = 0; i < 4; ++i) {
    const int lr = wm * 64 + i * 16 + r0 * 4;
    const int row = row0 + lr;
    const float4 z0 = *(const float4*)&zsqt[0][lr];
    const float4 z1 = *(const float4*)&zsqt[1][lr];
    const float4 z2 = *(const float4*)&zsqt[2][lr];
    const float4 z3 = *(const float4*)&zsqt[3][lr];
    const float sx = z0.x + z1.x + z2.x + z3.x;
    const float sy = z0.y + z1.y + z2.y + z3.y;
    const float sz = z0.z + z1.z + z2.z + z3.z;
    const float sw = z0.w + z1.w + z2.w + z3.w;
    #pragma unroll
    for (int j = 0; j < 2; ++j) {
      const int col = col0 + wn * 32 + j * 16 + c;
      const float es = esq[col];
      const float d0 = fmaxf(sx + es - 2.0f * acc[i][j][0], 0.0f);
      const float d1 = fmaxf(sy + es - 2.0f * acc[i][j][1], 0.0f);
      const float d2 = fmaxf(sz + es - 2.0f * acc[i][j][2], 0.0f);
      const float d3 = fmaxf(sw + es - 2.0f * acc[i][j][3], 0.0f);
      __builtin_nontemporal_store(d0, &out[(size_t)(row + 0) * MCODES + col]);
      __builtin_nontemporal_store(d1, &out[(size_t)(row + 1) * MCODES + col]);
      __builtin_nontemporal_store(d2, &out[(size_t)(row + 2) * MCODES + col]);
      __builtin_nontemporal_store(d3, &out[(size_t)(row + 3) * MCODES + col]);
      cmin[j] = fminf(cmin[j], fminf(fminf(d0, d1), fminf(d2, d3)));
    }
  }
  #pragma unroll
  for (int j = 0; j < 2; ++j) {
    float m = cmin[j];
    m = fminf(m, __shfl_xor(m, 16, 64));
    m = fminf(m, __shfl_xor(m, 32, 64));
    if (lane < 16) {
      const int col = col0 + wn * 32 + j * 16 + lane;
      atomicMin(colmin + col, __float_as_uint(m));   // dist>=0 -> uint order == float order
    }
  }
}

// ---------------- loss = mean(colmin) ----------------
__global__ void loss_k(const unsigned* __restrict__ colmin, float* __restrict__ loss) {
  __shared__ float sdata[4];
  int t = threadIdx.x;
  float s = 0.0f;
  for (int i = t; i < MCODES; i += 256) s += __uint_as_float(colmin[i]);
  #pragma unroll
  for (int off = 32; off; off >>= 1) s += __shfl_down(s, off, 64);
  if ((t & 63) == 0) sdata[t >> 6] = s;
  __syncthreads();
  if (t == 0) loss[0] = (sdata[0] + sdata[1] + sdata[2] + sdata[3]) * (1.0f / (float)MCODES);
}

extern "C" void kernel_launch(void* const* d_in, const int* in_sizes, int n_in,
                              void* d_out, int out_size, void* d_ws, size_t ws_size,
                              hipStream_t stream) {
  const float* z = (const float*)d_in[0];
  const float* e = (const float*)d_in[1];
  float* out = (float*)d_out;

  float* ws = (float*)d_ws;
  float* esq = ws;                                     // 2048 f
  unsigned* colmin = (unsigned*)(ws + MCODES);         // 2048 u32
  unsigned short* ebf = (unsigned short*)(ws + 2 * MCODES);  // 1 MB

  prep_e_k<<<MCODES / 4, 256, 0, stream>>>(e, ebf, esq, colmin);
  gemm_k<<<2048, 512, 0, stream>>>(z, ebf, esq, colmin, out);
  loss_k<<<1, 256, 0, stream>>>(colmin, out + (size_t)NTOT * MCODES);
}

// Round 8
// 185.164 us; speedup vs baseline: 1.3166x; 1.0610x over previous
//
#include <hip/hip_runtime.h>

typedef __attribute__((ext_vector_type(8))) short bf16x8;
typedef __attribute__((ext_vector_type(4))) float f32x4;

#define NTOT 16384
#define MCODES 2048
#define DDIM 256

__device__ __forceinline__ unsigned short f2bf(float f) {
  union { float f; unsigned u; } v; v.f = f;
  unsigned r = v.u + 0x7FFFu + ((v.u >> 16) & 1u);   // RNE
  return (unsigned short)(r >> 16);
}

#define GLOAD16(gptr, lptr) \
  __builtin_amdgcn_global_load_lds((const __attribute__((address_space(1))) void*)(gptr), \
                                   (__attribute__((address_space(3))) void*)(lptr), 16, 0, 0)

// ---------------- prep e: bf16 convert + ||e||^2 + colmin/zsq init ----------------
__global__ void prep_e_k(const float* __restrict__ e, unsigned short* __restrict__ ebf,
                         float* __restrict__ esq, unsigned* __restrict__ colmin,
                         float* __restrict__ zsq) {
  if (blockIdx.x < 64) zsq[blockIdx.x * 256 + threadIdx.x] = 0.0f;  // 64*256 = 16384
  int row = blockIdx.x * 4 + (threadIdx.x >> 6);
  int lane = threadIdx.x & 63;
  const float4 v = *(const float4*)(e + (size_t)row * DDIM + lane * 4);
  ushort4 o;
  o.x = f2bf(v.x); o.y = f2bf(v.y); o.z = f2bf(v.z); o.w = f2bf(v.w);
  *(ushort4*)(ebf + (size_t)row * DDIM + lane * 4) = o;
  float s = v.x * v.x + v.y * v.y + v.z * v.z + v.w * v.w;
  #pragma unroll
  for (int off = 32; off; off >>= 1) s += __shfl_xor(s, off, 64);
  if (lane == 0) {
    esq[row] = s;
    colmin[row] = 0x7F800000u;  // +inf
  }
}

// ---------------- transpose z (B,D,H,W) f32 -> (N,D) bf16, fused ||z||^2 ----------------
__global__ void trans_zsq_k(const float* __restrict__ z, unsigned short* __restrict__ zf,
                            float* __restrict__ zsq) {
  __shared__ float t[64][65];
  const int b = blockIdx.z, d0 = blockIdx.x * 64, hw0 = blockIdx.y * 64;
  const int tid = threadIdx.x;
  {
    const int dl = tid >> 4, hwl = (tid & 15) * 4;
    const float* src = z + (size_t)b * 262144 + (size_t)(d0 + dl) * 1024 + hw0 + hwl;
    #pragma unroll
    for (int it = 0; it < 4; ++it) {
      float4 v = *(const float4*)(src + (size_t)it * 16 * 1024);
      *(float4*)&t[it * 16 + dl][hwl] = v;
    }
  }
  __syncthreads();
  const int hwl = tid >> 3;                          // 0..31
  const int dl = (tid & 7) * 8;                      // 0..56 step 8
  #pragma unroll
  for (int p = 0; p < 2; ++p) {
    const int hw = p * 32 + hwl;
    float vv[8];
    float s = 0.0f;
    #pragma unroll
    for (int u = 0; u < 8; ++u) { vv[u] = t[dl + u][hw]; s += vv[u] * vv[u]; }
    bf16x8 pk;
    #pragma unroll
    for (int u = 0; u < 8; ++u) pk[u] = (short)f2bf(vv[u]);
    const size_t n = (size_t)b * 1024 + hw0 + hw;
    *(bf16x8*)(zf + n * DDIM + d0 + dl) = pk;
    s += __shfl_xor(s, 1, 64);
    s += __shfl_xor(s, 2, 64);
    s += __shfl_xor(s, 4, 64);
    if ((tid & 7) == 0) atomicAdd(zsq + n, s);
  }
}

// ---------------- GEMM 128x128, 4 waves (2x2, 64x64 each), BK=32 double-buffered ----------------
// Small LDS (32KB) + low VGPR -> 3 blocks/CU, 12 waves/CU: TLP hides latency (r1/r4 lesson).
// 1 barrier per K-tile (dbuf); source-side XOR swizzle with WAVE-UNIFORM LDS dest
// (rule #21/m104: global_load_lds writes base + lane*16; per-lane dest is illegal —
// that was round 5's inf bug). NT stores; XCD-chunked bid.
__global__ __launch_bounds__(256, 3) void gemm_k(
    const unsigned short* __restrict__ A,   // zf (N x 256) bf16
    const unsigned short* __restrict__ B,   // ebf (M x 256) bf16
    const float* __restrict__ zsq, const float* __restrict__ esq,
    unsigned* __restrict__ colmin, float* __restrict__ out) {
  __shared__ __align__(16) unsigned short As[2][128 * 32];   // 8KB per buf
  __shared__ __align__(16) unsigned short Bs[2][128 * 32];

  const int tid = threadIdx.x;
  const int wave = tid >> 6, lane = tid & 63;
  const int wm = wave >> 1, wn = wave & 1;

  // T1: XCD-chunked (2048 % 8 == 0, bijective). XCD owns 16 full row-panels.
  const int s_ = blockIdx.x >> 3, xcd = blockIdx.x & 7;
  const int col0 = (s_ & 15) * 128;
  const int row0 = ((s_ >> 4) + xcd * 16) * 128;

  // staging: per GLOAD16 call the wave covers 16 rows x 64B; lane l -> dest row
  // wave*32 + q*16 + (l>>2), dest chunk l&3. Source chunk pre-swizzled (l&3)^(row&3).
  const int sr_ = wave * 32 + (lane >> 2);               // q=0 row (q=1: +16, same &3)
  const int csw = ((lane & 3) ^ (sr_ & 3)) * 8;          // swizzled source k-offset (shorts)
  const size_t aOff0 = (size_t)(row0 + sr_) * DDIM + csw;
  const size_t aOff1 = (size_t)(row0 + sr_ + 16) * DDIM + csw;
  const size_t bOff0 = (size_t)(col0 + sr_) * DDIM + csw;
  const size_t bOff1 = (size_t)(col0 + sr_ + 16) * DDIM + csw;

  // fragment reads: row = w*64 + i*16 + fr; dest chunk = (lane>>4) ^ (row&3)
  const int fr = lane & 15;
  const int axor = ((lane >> 4) << 4) ^ ((fr & 3) << 4);

  f32x4 acc[4][4] = {};

  #define STAGE(buf, k0)                                                        \
    {                                                                           \
      GLOAD16(A + aOff0 + (k0), (unsigned short*)As[buf] + wave * 1024);        \
      GLOAD16(A + aOff1 + (k0), (unsigned short*)As[buf] + wave * 1024 + 512);  \
      GLOAD16(B + bOff0 + (k0), (unsigned short*)Bs[buf] + wave * 1024);        \
      GLOAD16(B + bOff1 + (k0), (unsigned short*)Bs[buf] + wave * 1024 + 512);  \
    }

  STAGE(0, 0);
  __syncthreads();

  #pragma unroll
  for (int t = 0; t < 8; ++t) {
    const int cur = t & 1;
    if (t < 7) STAGE(cur ^ 1, (t + 1) * 32);        // prefetch; drained by barrier below
    const char* pA = (const char*)As[cur];
    const char* pB = (const char*)Bs[cur];
    bf16x8 av[4], bv[4];
    #pragma unroll
    for (int i = 0; i < 4; ++i)
      av[i] = *(const bf16x8*)(pA + (wm * 64 + i * 16 + fr) * 64 + axor);
    #pragma unroll
    for (int j = 0; j < 4; ++j)
      bv[j] = *(const bf16x8*)(pB + (wn * 64 + j * 16 + fr) * 64 + axor);
    #pragma unroll
    for (int i = 0; i < 4; ++i)
      #pragma unroll
      for (int j = 0; j < 4; ++j)
        acc[i][j] = __builtin_amdgcn_mfma_f32_16x16x32_bf16(av[i], bv[j], acc[i][j], 0, 0, 0);
    if (t < 7) __syncthreads();
  }
  #undef STAGE

  // epilogue: dist = zsq + esq - 2*cross, clamp>=0, NT store + column-min
  const int r0 = lane >> 4, c = lane & 15;
  float cmin[4] = {3.4e38f, 3.4e38f, 3.4e38f, 3.4e38f};
  #pragma unroll
  for (int j = 0; j < 4; ++j) {
    const int col = col0 + wn * 64 + j * 16 + c;
    const float es = esq[col];
    #pragma unroll
    for (int i = 0; i < 4; ++i) {
      const int row = row0 + wm * 64 + i * 16 + r0 * 4;
      const float4 zs = *(const float4*)(zsq + row);
      const float d0 = fmaxf(zs.x + es - 2.0f * acc[i][j][0], 0.0f);
      const float d1 = fmaxf(zs.y + es - 2.0f * acc[i][j][1], 0.0f);
      const float d2 = fmaxf(zs.z + es - 2.0f * acc[i][j][2], 0.0f);
      const float d3 = fmaxf(zs.w + es - 2.0f * acc[i][j][3], 0.0f);
      __builtin_nontemporal_store(d0, &out[(size_t)(row + 0) * MCODES + col]);
      __builtin_nontemporal_store(d1, &out[(size_t)(row + 1) * MCODES + col]);
      __builtin_nontemporal_store(d2, &out[(size_t)(row + 2) * MCODES + col]);
      __builtin_nontemporal_store(d3, &out[(size_t)(row + 3) * MCODES + col]);
      cmin[j] = fminf(cmin[j], fminf(fminf(d0, d1), fminf(d2, d3)));
    }
  }
  #pragma unroll
  for (int j = 0; j < 4; ++j) {
    float m = cmin[j];
    m = fminf(m, __shfl_xor(m, 16, 64));
    m = fminf(m, __shfl_xor(m, 32, 64));
    if (lane < 16) {
      const int col = col0 + wn * 64 + j * 16 + lane;
      atomicMin(colmin + col, __float_as_uint(m));   // dist>=0 -> uint order == float order
    }
  }
}

// ---------------- loss = mean(colmin) ----------------
__global__ void loss_k(const unsigned* __restrict__ colmin, float* __restrict__ loss) {
  __shared__ float sdata[4];
  int t = threadIdx.x;
  float s = 0.0f;
  for (int i = t; i < MCODES; i += 256) s += __uint_as_float(colmin[i]);
  #pragma unroll
  for (int off = 32; off; off >>= 1) s += __shfl_down(s, off, 64);
  if ((t & 63) == 0) sdata[t >> 6] = s;
  __syncthreads();
  if (t == 0) loss[0] = (sdata[0] + sdata[1] + sdata[2] + sdata[3]) * (1.0f / (float)MCODES);
}

extern "C" void kernel_launch(void* const* d_in, const int* in_sizes, int n_in,
                              void* d_out, int out_size, void* d_ws, size_t ws_size,
                              hipStream_t stream) {
  const float* z = (const float*)d_in[0];
  const float* e = (const float*)d_in[1];
  float* out = (float*)d_out;

  float* ws = (float*)d_ws;
  float* zsq = ws;                                   // 16384 f
  float* esq = ws + NTOT;                            // 2048 f
  unsigned* colmin = (unsigned*)(ws + NTOT + MCODES);// 2048 u32
  unsigned short* ebf = (unsigned short*)(ws + NTOT + 2 * MCODES);  // 1 MB
  unsigned short* zf = ebf + (size_t)MCODES * DDIM;                 // 8 MB

  prep_e_k<<<MCODES / 4, 256, 0, stream>>>(e, ebf, esq, colmin, zsq);
  trans_zsq_k<<<dim3(4, 16, 16), 256, 0, stream>>>(z, zf, zsq);
  gemm_k<<<2048, 256, 0, stream>>>(zf, ebf, zsq, esq, colmin, out);
  loss_k<<<1, 256, 0, stream>>>(colmin, out + (size_t)NTOT * MCODES);
}